// Round 9
// baseline (314.280 us; speedup 1.0000x reference)
//
#include <hip/hip_runtime.h>

#define D 128
#define LEAKY 0.01f
#define SCAN_CHUNK 2048   // 256 threads x 8 elements

typedef __attribute__((ext_vector_type(8))) short short8;
typedef __attribute__((ext_vector_type(4))) float f32x4;

__device__ __forceinline__ unsigned short f2bf(float f) {
    unsigned u = __float_as_uint(f);
    u += 0x7fffu + ((u >> 16) & 1u);          // round-to-nearest-even
    return (unsigned short)(u >> 16);
}

// ---------------- W prep: f32 [k][col] -> bf16 [col][k], PRE-SWIZZLED ----------------

__global__ void k_wprep(const float* __restrict__ W1, const float* __restrict__ W2,
                        const float* __restrict__ W3, unsigned short* __restrict__ wtg) {
    int tid = blockIdx.x * 256 + threadIdx.x;
    if (tid >= 3 * 128 * 16) return;
    int col = tid & 127;
    int s   = (tid >> 7) & 15;    // granule: 8 consecutive k
    int w   = tid >> 11;
    const float* Ws = (w == 0) ? W1 : (w == 1) ? W2 : W3;
    unsigned un[4];
    #pragma unroll
    for (int p = 0; p < 4; p++) {
        float a = Ws[(s * 8 + 2 * p) * 128 + col];
        float b = Ws[(s * 8 + 2 * p + 1) * 128 + col];
        un[p] = (unsigned)f2bf(a) | ((unsigned)f2bf(b) << 16);
    }
    uint4 v = {un[0], un[1], un[2], un[3]};
    int byte = w * 32768 + col * 256 + ((s * 16) ^ ((col & 7) << 4));
    *(uint4*)((char*)wtg + byte) = v;
}

// ---------------- pass 1: rowsum over src (atomic) + dst histogram w/ rank ----------------
// 1 edge/thread; floor = memory-side atomic RMW throughput (~17G/s), measured r5/r6.

__global__ void k_pass1(const int* __restrict__ src, const int* __restrict__ dst,
                        const float* __restrict__ w, float* __restrict__ rowsum,
                        int* __restrict__ cnt, int* __restrict__ rank, int E) {
    int e = blockIdx.x * 256 + threadIdx.x;
    if (e >= E) return;
    atomicAdd(&rowsum[src[e]], w[e]);
    rank[e] = atomicAdd(&cnt[dst[e]], 1);
}

// ---------------- prefix scan (3-phase) over cnt[N] -> start[N+1] ----------------

__global__ void k_chunk_sum(const int* __restrict__ cnt, int* __restrict__ partial, int n) {
    __shared__ int sdata[256];
    int b = blockIdx.x;
    int base = b * SCAN_CHUNK;
    int s = 0;
    for (int i = threadIdx.x; i < SCAN_CHUNK; i += 256) {
        int idx = base + i;
        s += (idx < n) ? cnt[idx] : 0;
    }
    sdata[threadIdx.x] = s;
    __syncthreads();
    for (int off = 128; off > 0; off >>= 1) {
        if (threadIdx.x < off) sdata[threadIdx.x] += sdata[threadIdx.x + off];
        __syncthreads();
    }
    if (threadIdx.x == 0) partial[b] = sdata[0];
}

__global__ void k_scan_partial(int* __restrict__ partial, int nchunks) {
    if (blockIdx.x == 0 && threadIdx.x == 0) {
        int run = 0;
        for (int i = 0; i < nchunks; i++) { int v = partial[i]; partial[i] = run; run += v; }
    }
}

__global__ void k_chunk_scan(const int* __restrict__ cnt, const int* __restrict__ partial,
                             int* __restrict__ start, int n, int total) {
    __shared__ int sdata[256];
    int b = blockIdx.x;
    int base = b * SCAN_CHUNK;
    int t = threadIdx.x;
    int loc[8];
    int s = 0;
    int tb = base + t * 8;
    #pragma unroll
    for (int j = 0; j < 8; j++) {
        int idx = tb + j;
        int v = (idx < n) ? cnt[idx] : 0;
        loc[j] = s;
        s += v;
    }
    sdata[t] = s;
    __syncthreads();
    for (int off = 1; off < 256; off <<= 1) {
        int v = (t >= off) ? sdata[t - off] : 0;
        __syncthreads();
        sdata[t] += v;
        __syncthreads();
    }
    int texcl = (t == 0) ? 0 : sdata[t - 1];
    int offb = partial[b];
    #pragma unroll
    for (int j = 0; j < 8; j++) {
        int idx = tb + j;
        if (idx < n) start[idx] = offb + texcl + loc[j];
    }
    if (b == gridDim.x - 1 && t == 255) start[n] = total;
}

// ---------------- scatter (NO atomics): compute w_hat, place at start[d]+rank[e] ----------------

__global__ void k_scatter2(const int* __restrict__ src, const int* __restrict__ dst,
                           const float* __restrict__ w, const float* __restrict__ rowsum,
                           const int* __restrict__ start, const int* __restrict__ rank,
                           int2* __restrict__ csr, int E) {
    int e = blockIdx.x * 256 + threadIdx.x;
    if (e >= E) return;
    int s = src[e], d = dst[e];
    float rs = rowsum[s], rd = rowsum[d];
    float wh = w[e] * (rs > 0.f ? 1.f / rs : 0.f) * (rd > 0.f ? 1.f / rd : 0.f);
    int idx = start[d] + rank[e];
    csr[idx] = make_int2(s, __float_as_int(wh));
}

// ---------------- deg via contiguous segment gather (no atomics) -> dinv ----------------

__global__ void k_deg_dinv(const int2* __restrict__ csr, const int* __restrict__ start,
                           float* __restrict__ dinv, int N) {
    int n = blockIdx.x * 256 + threadIdx.x;
    if (n >= N) return;
    int s0 = start[n], s1 = start[n + 1];
    float s = 0.f;
    for (int i = s0; i < s1; i++) s += __int_as_float(csr[i].y);
    dinv[n] = s > 0.f ? rsqrtf(s) : 0.f;
}

// ---------------- shared agg inner loop (bf16 gather, f32 accum) ----------------
// 16 lanes per node; lane l owns cols 8l..8l+7 (one uint4 = 8 bf16 per row).
// NORM=1: csr holds raw w_hat; apply dinv[src]*dinv[dst] on the fly, write back.

__device__ __forceinline__ void fma8(float* acc, float n, uint4 v) {
    acc[0] += n * __uint_as_float(v.x << 16);
    acc[1] += n * __uint_as_float(v.x & 0xffff0000u);
    acc[2] += n * __uint_as_float(v.y << 16);
    acc[3] += n * __uint_as_float(v.y & 0xffff0000u);
    acc[4] += n * __uint_as_float(v.z << 16);
    acc[5] += n * __uint_as_float(v.z & 0xffff0000u);
    acc[6] += n * __uint_as_float(v.w << 16);
    acc[7] += n * __uint_as_float(v.w & 0xffff0000u);
}

template<int NORM>
__device__ __forceinline__ void agg_accum(const uint4* __restrict__ Y4, int2* __restrict__ csr,
                                          int s0, int cnt, int l,
                                          const float* __restrict__ dinv, float ddst,
                                          float* acc) {
    for (int base = 0; base < cnt; base += 16) {
        int rem = cnt - base; if (rem > 16) rem = 16;
        int eidx = s0 + base + l;
        int2 pr = (l < rem) ? csr[eidx] : make_int2(0, 0);
        int  sj = pr.x;
        float nj = __int_as_float(pr.y);
        if (NORM) {
            nj = nj * dinv[sj] * ddst;               // l>=rem: nj=0 stays 0
            if (l < rem) csr[eidx] = make_int2(sj, __float_as_int(nj));
        }
        int j = 0;
        for (; j + 8 <= rem; j += 8) {
            int   i0 = __shfl(sj, j + 0, 16), i1 = __shfl(sj, j + 1, 16);
            int   i2 = __shfl(sj, j + 2, 16), i3 = __shfl(sj, j + 3, 16);
            int   i4 = __shfl(sj, j + 4, 16), i5 = __shfl(sj, j + 5, 16);
            int   i6 = __shfl(sj, j + 6, 16), i7 = __shfl(sj, j + 7, 16);
            float n0 = __shfl(nj, j + 0, 16), n1 = __shfl(nj, j + 1, 16);
            float n2 = __shfl(nj, j + 2, 16), n3 = __shfl(nj, j + 3, 16);
            float n4 = __shfl(nj, j + 4, 16), n5 = __shfl(nj, j + 5, 16);
            float n6 = __shfl(nj, j + 6, 16), n7 = __shfl(nj, j + 7, 16);
            uint4 v0 = Y4[(size_t)i0 * 16 + l];
            uint4 v1 = Y4[(size_t)i1 * 16 + l];
            uint4 v2 = Y4[(size_t)i2 * 16 + l];
            uint4 v3 = Y4[(size_t)i3 * 16 + l];
            uint4 v4 = Y4[(size_t)i4 * 16 + l];
            uint4 v5 = Y4[(size_t)i5 * 16 + l];
            uint4 v6 = Y4[(size_t)i6 * 16 + l];
            uint4 v7 = Y4[(size_t)i7 * 16 + l];
            fma8(acc, n0, v0); fma8(acc, n1, v1);
            fma8(acc, n2, v2); fma8(acc, n3, v3);
            fma8(acc, n4, v4); fma8(acc, n5, v5);
            fma8(acc, n6, v6); fma8(acc, n7, v7);
        }
        for (; j + 4 <= rem; j += 4) {
            int   i0 = __shfl(sj, j + 0, 16), i1 = __shfl(sj, j + 1, 16);
            int   i2 = __shfl(sj, j + 2, 16), i3 = __shfl(sj, j + 3, 16);
            float n0 = __shfl(nj, j + 0, 16), n1 = __shfl(nj, j + 1, 16);
            float n2 = __shfl(nj, j + 2, 16), n3 = __shfl(nj, j + 3, 16);
            uint4 v0 = Y4[(size_t)i0 * 16 + l];
            uint4 v1 = Y4[(size_t)i1 * 16 + l];
            uint4 v2 = Y4[(size_t)i2 * 16 + l];
            uint4 v3 = Y4[(size_t)i3 * 16 + l];
            fma8(acc, n0, v0); fma8(acc, n1, v1);
            fma8(acc, n2, v2); fma8(acc, n3, v3);
        }
        for (; j < rem; j++) {
            int   i0 = __shfl(sj, j, 16);
            float n0 = __shfl(nj, j, 16);
            uint4 v0 = Y4[(size_t)i0 * 16 + l];
            fma8(acc, n0, v0);
        }
    }
}

// ---------------- fused agg + GEMM ----------------
// Block = 256 thr = 4 waves = 64 nodes. Phase 1: each 16-lane group aggregates 4
// nodes (bias+leaky+bf16) directly into the swizzled LDS X-tile. Phase 2: MFMA
// with pre-swizzled W, write Yb_out rows. Yb_out must not alias Yb_prev.

template<int NORM>
__global__ __launch_bounds__(256) void k_agg_gemm(const unsigned short* __restrict__ Yb_prev,
                                                  int2* __restrict__ csr,
                                                  const int* __restrict__ start,
                                                  const float* __restrict__ dinv,
                                                  const float* __restrict__ bias,
                                                  const unsigned short* __restrict__ Wtg,
                                                  unsigned short* __restrict__ Yb_out, int N) {
    __shared__ unsigned short Wt[128 * 128];   // 32KB
    __shared__ unsigned short Xs[64 * 128];    // 16KB
    int t = threadIdx.x;
    int rowbase = blockIdx.x * 64;

    // stage W: linear copy of pre-swizzled layout (completes under gather latency)
    {
        const uint4* Wg = (const uint4*)Wtg;
        uint4* Wl = (uint4*)Wt;
        #pragma unroll
        for (int i = 0; i < 8; i++) Wl[t + i * 256] = Wg[t + i * 256];
    }

    int lane = t & 63;
    int wv = t >> 6;
    int g = lane >> 4;
    int l = lane & 15;
    int G = wv * 4 + g;                        // group 0..15, 4 nodes each
    const uint4* Y4 = (const uint4*)Yb_prev;
    float4 ba = ((const float4*)bias)[l * 2];
    float4 bb = ((const float4*)bias)[l * 2 + 1];

    for (int i = 0; i < 4; i++) {
        int r = G * 4 + i;                     // 0..63
        int node = rowbase + r;
        bool valid = node < N;
        int s0 = valid ? start[node] : 0;
        int s1 = valid ? start[node + 1] : 0;
        int cnt = s1 - s0;
        float ddst = 0.f;
        if (NORM) ddst = valid ? dinv[node] : 0.f;

        float acc[8] = {};
        agg_accum<NORM>(Y4, csr, s0, cnt, l, dinv, ddst, acc);

        float o[8];
        o[0] = acc[0] + ba.x; o[1] = acc[1] + ba.y; o[2] = acc[2] + ba.z; o[3] = acc[3] + ba.w;
        o[4] = acc[4] + bb.x; o[5] = acc[5] + bb.y; o[6] = acc[6] + bb.z; o[7] = acc[7] + bb.w;
        #pragma unroll
        for (int k = 0; k < 8; k++) o[k] = o[k] > 0.f ? o[k] : LEAKY * o[k];
        uint4 ov;
        ov.x = (unsigned)f2bf(o[0]) | ((unsigned)f2bf(o[1]) << 16);
        ov.y = (unsigned)f2bf(o[2]) | ((unsigned)f2bf(o[3]) << 16);
        ov.z = (unsigned)f2bf(o[4]) | ((unsigned)f2bf(o[5]) << 16);
        ov.w = (unsigned)f2bf(o[6]) | ((unsigned)f2bf(o[7]) << 16);
        int byte = r * 256 + ((l * 16) ^ ((r & 7) << 4));
        *(uint4*)((char*)Xs + byte) = ov;      // unconditional: invalid rows = act(bias)
    }
    __syncthreads();

    // MFMA phase
    int r0 = wv * 16;
    int lr = lane & 15, lg = lane >> 4;

    short8 a[4];
    {
        int row = r0 + lr;
        const char* rp = (const char*)Xs + row * 256;
        int sw = (row & 7) << 4;
        #pragma unroll
        for (int s = 0; s < 4; s++)
            a[s] = *(const short8*)(rp + ((s * 64 + lg * 16) ^ sw));
    }

    f32x4 accv[8];
    #pragma unroll
    for (int ct = 0; ct < 8; ct++) {
        f32x4 c = {0.f, 0.f, 0.f, 0.f};
        int col = ct * 16 + lr;
        const char* cp = (const char*)Wt + col * 256;
        int sw = (col & 7) << 4;
        #pragma unroll
        for (int s = 0; s < 4; s++) {
            short8 b = *(const short8*)(cp + ((s * 64 + lg * 16) ^ sw));
            c = __builtin_amdgcn_mfma_f32_16x16x32_bf16(a[s], b, c, 0, 0, 0);
        }
        accv[ct] = c;
    }

    #pragma unroll
    for (int j = 0; j < 4; j++) {
        int row = rowbase + r0 + lg * 4 + j;
        if (row < N) {
            #pragma unroll
            for (int ct = 0; ct < 8; ct++)
                Yb_out[(size_t)row * 128 + ct * 16 + lr] = f2bf(accv[ct][j]);
        }
    }
}

// ---------------- MFMA GEMM (layer 1 only): Yb = rownorm(feat) @ W1 ----------------

#define GR 64

__global__ __launch_bounds__(256) void k_gemm1(const float* __restrict__ Xf32,
                                               const unsigned short* __restrict__ Wtg,
                                               unsigned short* __restrict__ Yb, int nrows) {
    __shared__ unsigned short Wt[128 * 128];
    __shared__ unsigned short Xs[GR * 128];
    int t = threadIdx.x;
    int rowbase = blockIdx.x * GR;

    {
        const uint4* Wg = (const uint4*)Wtg;
        uint4* Wl = (uint4*)Wt;
        #pragma unroll
        for (int i = 0; i < 8; i++) Wl[t + i * 256] = Wg[t + i * 256];
    }

    // 4 threads per row; thread q owns float4s {q, q+4, ..., q+28}
    {
        int r = t >> 2, q = t & 3;
        int row = rowbase + r;
        const float4* Xr = (const float4*)(Xf32 + (size_t)row * 128);
        float4 v[8];
        float s = 0.f;
        #pragma unroll
        for (int k = 0; k < 8; k++) {
            float4 x = make_float4(0.f, 0.f, 0.f, 0.f);
            if (row < nrows) x = Xr[q + k * 4];
            v[k] = x;
            s += x.x + x.y + x.z + x.w;
        }
        s += __shfl_down(s, 2, 4);
        s += __shfl_down(s, 1, 4);
        float tot = __shfl(s, 0, 4);
        float inv = tot > 0.f ? 1.f / tot : 0.f;
        int sw = (r & 7) << 4;
        #pragma unroll
        for (int k = 0; k < 8; k++) {
            int gidx = q + k * 4;
            ushort4 h;
            h.x = f2bf(v[k].x * inv); h.y = f2bf(v[k].y * inv);
            h.z = f2bf(v[k].z * inv); h.w = f2bf(v[k].w * inv);
            *(ushort4*)((char*)Xs + r * 256 + ((gidx * 8) ^ sw)) = h;
        }
    }
    __syncthreads();

    int w = t >> 6, l = t & 63;
    int r0 = w * 16;
    int lr = l & 15, lg = l >> 4;

    short8 a[4];
    {
        int row = r0 + lr;
        const char* rp = (const char*)Xs + row * 256;
        int sw = (row & 7) << 4;
        #pragma unroll
        for (int s = 0; s < 4; s++)
            a[s] = *(const short8*)(rp + ((s * 64 + lg * 16) ^ sw));
    }

    f32x4 acc[8];
    #pragma unroll
    for (int ct = 0; ct < 8; ct++) {
        f32x4 c = {0.f, 0.f, 0.f, 0.f};
        int col = ct * 16 + lr;
        const char* cp = (const char*)Wt + col * 256;
        int sw = (col & 7) << 4;
        #pragma unroll
        for (int s = 0; s < 4; s++) {
            short8 b = *(const short8*)(cp + ((s * 64 + lg * 16) ^ sw));
            c = __builtin_amdgcn_mfma_f32_16x16x32_bf16(a[s], b, c, 0, 0, 0);
        }
        acc[ct] = c;
    }

    #pragma unroll
    for (int j = 0; j < 4; j++) {
        int row = rowbase + r0 + lg * 4 + j;
        if (row < nrows) {
            #pragma unroll
            for (int ct = 0; ct < 8; ct++)
                Yb[(size_t)row * 128 + ct * 16 + lr] = f2bf(acc[ct][j]);
        }
    }
}

// ---------------- final aggregation: f32 out, no activation ----------------
// 4 nodes/wave as before.

__global__ void k_agg_final(const unsigned short* __restrict__ Yb, int2* __restrict__ csr,
                            const int* __restrict__ start, const float* __restrict__ bias,
                            float* __restrict__ OutF, int N) {
    int wid = (blockIdx.x * blockDim.x + threadIdx.x) >> 6;
    int lane = threadIdx.x & 63;
    int g = lane >> 4;
    int l = lane & 15;
    int node = wid * 4 + g;
    bool valid = node < N;
    int s0 = valid ? start[node] : 0;
    int s1 = valid ? start[node + 1] : 0;
    int cnt = s1 - s0;

    float acc[8] = {};
    agg_accum<0>((const uint4*)Yb, csr, s0, cnt, l, nullptr, 0.f, acc);

    if (!valid) return;
    float4 ba = ((const float4*)bias)[l * 2];
    float4 bb = ((const float4*)bias)[l * 2 + 1];
    float4 w0 = {acc[0] + ba.x, acc[1] + ba.y, acc[2] + ba.z, acc[3] + ba.w};
    float4 w1 = {acc[4] + bb.x, acc[5] + bb.y, acc[6] + bb.z, acc[7] + bb.w};
    ((float4*)OutF)[(size_t)node * 32 + l * 2] = w0;
    ((float4*)OutF)[(size_t)node * 32 + l * 2 + 1] = w1;
}

// ---------------- launch ----------------

extern "C" void kernel_launch(void* const* d_in, const int* in_sizes, int n_in,
                              void* d_out, int out_size, void* d_ws, size_t ws_size,
                              hipStream_t stream) {
    const float* feat = (const float*)d_in[0];
    const int*   eidx = (const int*)d_in[1];
    const float* ew   = (const float*)d_in[2];
    const float* W1   = (const float*)d_in[3];
    const float* b1   = (const float*)d_in[4];
    const float* W2   = (const float*)d_in[5];
    const float* b2   = (const float*)d_in[6];
    const float* W3   = (const float*)d_in[7];
    const float* b3   = (const float*)d_in[8];

    const int N = in_sizes[0] / D;   // 50000
    const int E = in_sizes[2];       // 600000
    const int* src = eidx;
    const int* dst = eidx + E;

    // workspace layout (4B units)
    size_t off = 0;
    char* base = (char*)d_ws;
    auto alloc4 = [&](size_t elems) -> void* {
        void* p = base + off * 4;
        off += (elems + 3) & ~(size_t)3;
        return p;
    };
    float* rowsum = (float*)alloc4(N);      // zeroed
    int*   cnt    = (int*)  alloc4(N);      // zeroed (contiguous with rowsum)
    char*  zero_end = base + off * 4;
    int*   start  = (int*)  alloc4(N + 1);
    float* dinv   = (float*)alloc4(N);
    int*   partial= (int*)  alloc4(64);
    int*   rank   = (int*)  alloc4(E);
    int2*  csr    = (int2*) alloc4((size_t)E * 2);
    unsigned short* wtg = (unsigned short*)alloc4(24576);          // 3 x 128x128 bf16, pre-swizzled
    unsigned short* xb  = (unsigned short*)alloc4((size_t)N * 64); // N x 128 bf16
    unsigned short* yb  = (unsigned short*)alloc4((size_t)N * 64);
    float* outp = (float*)d_out;

    hipMemsetAsync(rowsum, 0, (size_t)(zero_end - (char*)rowsum), stream);

    int eblocks = (E + 255) / 256;
    int nchunks = (N + SCAN_CHUNK - 1) / SCAN_CHUNK;
    int nblocks = (N + 255) / 256;
    int ablocks = (((N + 3) / 4) * 64 + 255) / 256; // agg_final: 4 nodes per wave
    int gblocks = (N + 63) / 64;

    k_wprep<<<24, 256, 0, stream>>>(W1, W2, W3, wtg);
    k_pass1<<<eblocks, 256, 0, stream>>>(src, dst, ew, rowsum, cnt, rank, E);

    k_chunk_sum<<<nchunks, 256, 0, stream>>>(cnt, partial, N);
    k_scan_partial<<<1, 64, 0, stream>>>(partial, nchunks);
    k_chunk_scan<<<nchunks, 256, 0, stream>>>(cnt, partial, start, N, E);

    k_scatter2<<<eblocks, 256, 0, stream>>>(src, dst, ew, rowsum, start, rank, csr, E);
    k_deg_dinv<<<nblocks, 256, 0, stream>>>(csr, start, dinv, N);

    // L1 GEMM: feat -> xb (fused row-normalize)
    k_gemm1<<<gblocks, 256, 0, stream>>>(feat, wtg, xb, N);
    // L1 agg (fused csr-norm) + L2 GEMM: xb -> yb
    k_agg_gemm<1><<<gblocks, 256, 0, stream>>>(xb, csr, start, dinv, b1, wtg + 16384, yb, N);
    // L2 agg + L3 GEMM: yb -> xb
    k_agg_gemm<0><<<gblocks, 256, 0, stream>>>(yb, csr, start, nullptr, b2, wtg + 32768, xb, N);
    // L3 agg -> d_out (f32, no activation)
    k_agg_final<<<ablocks, 256, 0, stream>>>(xb, csr, start, b3, outp, N);
}